// Round 1
// 1161.629 us; speedup vs baseline: 1.0001x; 1.0001x over previous
//
#include <hip/hip_runtime.h>

#define NSEG 8
#define SEGSH 19 // k_bucket: deg segment = edge >> 19
#define NGRP 8   // dst-range groups; group = blockIdx%8 -> fixed XCD
#define VPT 8    // k_bucket edges per thread (2048/block)
#define CSTR 64  // colsum element stride (256B) -> spread across L2 slices

typedef float    f2 __attribute__((ext_vector_type(2)));
typedef float    f4 __attribute__((ext_vector_type(4)));
typedef float    f8 __attribute__((ext_vector_type(8)));
typedef _Float16 h8 __attribute__((ext_vector_type(8)));

__device__ __forceinline__ unsigned f2key(float x){
  unsigned b = __float_as_uint(x);
  return (b & 0x80000000u) ? ~b : (b | 0x80000000u);
}
__device__ __forceinline__ float key2f(unsigned k){
  return (k & 0x80000000u) ? __uint_as_float(k ^ 0x80000000u) : __uint_as_float(~k);
}

// fp8 e4m3 HW decode: 4 bytes -> 4 floats
__device__ __forceinline__ f4 dec4(unsigned w){
  f2 a = __builtin_amdgcn_cvt_pk_f32_fp8((int)w, false);
  f2 b = __builtin_amdgcn_cvt_pk_f32_fp8((int)w, true);
  f4 r; r[0]=a[0]; r[1]=a[1]; r[2]=b[0]; r[3]=b[1];
  return r;
}
__device__ __forceinline__ f8 dec8(uint2 w){
  f4 lo = dec4(w.x), hi = dec4(w.y);
  f8 r;
  r[0]=lo[0]; r[1]=lo[1]; r[2]=lo[2]; r[3]=lo[3];
  r[4]=hi[0]; r[5]=hi[1]; r[6]=hi[2]; r[7]=hi[3];
  return r;
}

// ---------------- CSR build, bucketed (R13): one streaming pass does deg atomics +
//  dst-range bucketing (packed (dl<<17)|src, valid for N<=131072, span<=16384).
//  Fill pass reads only its own XCD's bucket -> csr write lines survive in L2.
//  Replaces 8x dst re-read (100MB F) + 13x csr write-amp (173MB W) of old k_fill. ----------------

__global__ __launch_bounds__(256) void k_bucket(const int* __restrict__ ei,
    int* __restrict__ deg8, int* __restrict__ bcur, int* __restrict__ bucket,
    int E, int n, int span, int cap){
  __shared__ int lcnt[NGRP];
  __shared__ int lbase[NGRP];
  int tid = threadIdx.x;
  if (tid < NGRP) lcnt[tid] = 0;
  __syncthreads();
  int base = blockIdx.x * (256*VPT);
  int val[VPT], meta[VPT];
  #pragma unroll
  for (int i=0;i<VPT;i++){
    int e = base + i*256 + tid;
    meta[i] = -1;
    if (e < E){
      int d = ei[E + e];
      int s = ei[e];
      if ((unsigned)d < (unsigned)n){
        int seg = e >> SEGSH; if (seg > NSEG-1) seg = NSEG-1;
        atomicAdd(&deg8[seg*n + d], 1);
        if ((unsigned)s < (unsigned)n){
          int g  = d / span;
          int dl = d - g*span;
          val[i]  = (dl << 17) | s;          // dl < 16384, s < 131072
          int rank = atomicAdd(&lcnt[g], 1); // rank < 2048 -> 12 bits
          meta[i] = (g << 12) | rank;
        }
      }
    }
  }
  __syncthreads();
  if (tid < NGRP){
    int c = lcnt[tid];
    lbase[tid] = (c > 0) ? atomicAdd(&bcur[tid], c) : 0;
  }
  __syncthreads();
  #pragma unroll
  for (int i=0;i<VPT;i++){
    if (meta[i] >= 0){
      int g   = meta[i] >> 12;
      int idx = lbase[g] + (meta[i] & 0xFFF);
      if (idx < cap) bucket[(size_t)g*cap + idx] = val[i];
    }
  }
}

__global__ __launch_bounds__(1024) void k_scan1(const int* __restrict__ deg8, int* __restrict__ offs,
                                                int* __restrict__ bsum, int n){
  __shared__ int tmp[1024];
  int tid = threadIdx.x;
  int gid = blockIdx.x*1024 + tid;
  int v = 0;
  if (gid < n){
    #pragma unroll
    for (int s=0;s<NSEG;s++) v += deg8[s*n + gid];
  }
  tmp[tid] = v;
  __syncthreads();
  for (int o=1;o<1024;o<<=1){
    int t = (tid>=o) ? tmp[tid-o] : 0;
    __syncthreads();
    if (tid>=o) tmp[tid] += t;
    __syncthreads();
  }
  int inc = tmp[tid];
  if (gid < n) offs[gid] = inc - v;   // exclusive within chunk
  if (tid == 1023) bsum[blockIdx.x] = inc;
}

__global__ void k_scan2(const int* __restrict__ bsum, int* __restrict__ bpre, int nb){
  if (threadIdx.x==0 && blockIdx.x==0){
    int acc=0;
    for (int i=0;i<nb;i++){ bpre[i]=acc; acc+=bsum[i]; }
  }
}

__global__ void k_scan3(int* __restrict__ offs, const int* __restrict__ bpre,
                        const int* __restrict__ deg8, int* __restrict__ cursor,
                        float* __restrict__ invdeg, int n, int E){
  int gid = blockIdx.x*blockDim.x + threadIdx.x;
  if (gid < n){
    int base = offs[gid] + bpre[gid>>10];
    offs[gid] = base;
    cursor[gid] = base;
    int dtot = 0;
    #pragma unroll
    for (int s=0;s<NSEG;s++) dtot += deg8[s*n + gid];
    invdeg[gid] = (dtot>0) ? 1.0f/(float)dtot : 0.0f;  // 0 marks isolated node (ref avg = 0)
  }
  if (gid==0) offs[n] = E;
}

__global__ __launch_bounds__(256) void k_fill2(const int* __restrict__ bucket,
    const int* __restrict__ bcur, int* __restrict__ cursor, int* __restrict__ csr,
    int E, int n, int span, int cap, int nstride){
  int g = blockIdx.x & (NGRP-1);
  int j = blockIdx.x >> 3;           // NGRP == 8
  int tid = threadIdx.x;
  int cnt = bcur[g]; if (cnt > cap) cnt = cap;
  int lo = g * span;
  const int* bp = bucket + (size_t)g*cap;
  int cnt4 = cnt >> 2;
  for (int i4 = j*256 + tid; i4 < cnt4; i4 += nstride){
    int4 v4 = ((const int4*)bp)[i4];
    int d0 = lo + (v4.x >> 17), s0 = v4.x & 0x1FFFF;
    int d1 = lo + (v4.y >> 17), s1 = v4.y & 0x1FFFF;
    int d2 = lo + (v4.z >> 17), s2 = v4.z & 0x1FFFF;
    int d3 = lo + (v4.w >> 17), s3 = v4.w & 0x1FFFF;
    int p0 = atomicAdd(&cursor[d0], 1);
    int p1 = atomicAdd(&cursor[d1], 1);
    int p2 = atomicAdd(&cursor[d2], 1);
    int p3 = atomicAdd(&cursor[d3], 1);
    if ((unsigned)p0 < (unsigned)E) csr[p0] = s0;
    if ((unsigned)p1 < (unsigned)E) csr[p1] = s1;
    if ((unsigned)p2 < (unsigned)E) csr[p2] = s2;
    if ((unsigned)p3 < (unsigned)E) csr[p3] = s3;
  }
  if (j == 0 && tid < (cnt & 3)){
    int i = (cnt & ~3) + tid;
    int v = bp[i];
    int d = lo + (v >> 17);
    int s = v & 0x1FFFF;
    int pos = atomicAdd(&cursor[d], 1);
    if ((unsigned)pos < (unsigned)E) csr[pos] = s;
  }
}

// ---------------- proj_in: gather x[4] + (avg@A + x@B) + row softmax -> store p as fp8 (base 0) ----------------

__global__ __launch_bounds__(256) void k_in(const float* __restrict__ x, unsigned char* __restrict__ uout,
    const int* __restrict__ offs, const int* __restrict__ csr, const float* __restrict__ invdeg,
    const float* __restrict__ A, const float* __restrict__ B, int n){
  __shared__ float sA[128], sB[128];
  int tid = threadIdx.x;
  if (tid < 128){ sA[tid]=A[tid]; sB[tid]=B[tid]; }
  __syncthreads();
  int node = blockIdx.x*256 + tid;
  if (node >= n) return;
  float4 s = {0,0,0,0};
  int b0=offs[node], e0=offs[node+1];
  for (int k=b0;k<e0;k++){
    int sid = csr[k];
    float4 v = ((const float4*)x)[sid];
    s.x+=v.x; s.y+=v.y; s.z+=v.z; s.w+=v.w;
  }
  float idg = invdeg[node];
  s.x*=idg; s.y*=idg; s.z*=idg; s.w*=idg;
  float4 xr = ((const float4*)x)[node];
  float z[32];
  #pragma unroll
  for (int j=0;j<32;j++){
    z[j] = s.x*sA[j] + s.y*sA[32+j] + s.z*sA[64+j] + s.w*sA[96+j]
         + xr.x*sB[j] + xr.y*sB[32+j] + xr.z*sB[64+j] + xr.w*sB[96+j];
  }
  float m = z[0];
  #pragma unroll
  for (int j=1;j<32;j++) m = fmaxf(m,z[j]);
  float sum=0.0f;
  #pragma unroll
  for (int j=0;j<32;j++){ z[j]=expf(z[j]-m); sum+=z[j]; }
  float r = 1.0f/sum;
  unsigned pk[8];
  #pragma unroll
  for (int q=0;q<8;q++){
    int w0 = __builtin_amdgcn_cvt_pk_fp8_f32(z[4*q]*r,   z[4*q+1]*r, 0,  false);
    w0     = __builtin_amdgcn_cvt_pk_fp8_f32(z[4*q+2]*r, z[4*q+3]*r, w0, true);
    pk[q] = (unsigned)w0;
  }
  uint4* op = (uint4*)(uout + (size_t)node*32);
  op[0] = make_uint4(pk[0],pk[1],pk[2],pk[3]);
  op[1] = make_uint4(pk[4],pk[5],pk[6],pk[7]);
}

// ---------------- conv round (MFMA, fp8 state): wave = 16 nodes. Plain loads. Output tile
//  staged in LDS -> coalesced 8B/lane stores. Structural floor: one random 32B row-request
//  per edge, throughput = E x L2-latency / (CUs x MSHRs) ~ 50us/round; invariant to payload
//  size (R6), cache placement (R9), and lane utilization (R12). ----------------

__global__ __launch_bounds__(256) void k_conv(
    const unsigned char* __restrict__ uin, unsigned char* __restrict__ uout,
    const int* __restrict__ offs, const int* __restrict__ csr,
    const float* __restrict__ invdeg,
    const float* __restrict__ Wa, const float* __restrict__ Wb,
    const float* __restrict__ cs_prev, float Rscale, float base,
    float* __restrict__ cs_next, int n){
  __shared__ float sWa[1024], sWb[1024];
  __shared__ float sCol[32];
  __shared__ unsigned char sU[64][32];
  int tid = threadIdx.x;
  float rcf = 1.0f;
  if (cs_prev) rcf = 131072.0f / ((float)n + cs_prev[(tid>>3)*CSTR]);  // rho = 2^17/colsum
  ((f4*)sWa)[tid] = ((const f4*)Wa)[tid] * rcf;
  ((f4*)sWb)[tid] = ((const f4*)Wb)[tid] * rcf;
  if (tid < 32) sCol[tid] = 0.0f;
  __syncthreads();

  int lane = tid & 63;
  int wv   = tid >> 6;
  int q    = lane >> 4;         // k-chunk (A) / row-quad (C)
  int c    = lane & 15;         // gather node (A's m) / output column (B's n, C's col)
  int tile = blockIdx.x*64 + wv*16;
  int node = tile + c;
  bool gv = node < n;

  // B-fragments in registers: B[k][n], k = q*8+j, n = c (lo) / c+16 (hi)
  h8 waLo, waHi, wbLo, wbHi;
  #pragma unroll
  for (int j=0;j<8;j++){
    int k = q*8 + j;
    waLo[j] = (_Float16)sWa[k*32 + c];
    waHi[j] = (_Float16)sWa[k*32 + c + 16];
    wbLo[j] = (_Float16)sWb[k*32 + c];
    wbHi[j] = (_Float16)sWb[k*32 + c + 16];
  }

  // gather: mean of neighbor v rows (fp8 decode), 8 plain loads in flight per lane
  f8 a0 = {0,0,0,0,0,0,0,0}, a1 = {0,0,0,0,0,0,0,0};
  f8 a2 = {0,0,0,0,0,0,0,0}, a3 = {0,0,0,0,0,0,0,0};
  int b0 = gv ? offs[node]   : 0;
  int e0 = gv ? offs[node+1] : 0;
  const uint2* ub = (const uint2*)uin;
  int k = b0;
  for (; k+8<=e0; k+=8){
    int s0=csr[k],   s1=csr[k+1], s2=csr[k+2], s3=csr[k+3];
    int s4=csr[k+4], s5=csr[k+5], s6=csr[k+6], s7=csr[k+7];
    uint2 v0 = ub[(size_t)s0*4 + q];
    uint2 v1 = ub[(size_t)s1*4 + q];
    uint2 v2 = ub[(size_t)s2*4 + q];
    uint2 v3 = ub[(size_t)s3*4 + q];
    uint2 v4 = ub[(size_t)s4*4 + q];
    uint2 v5 = ub[(size_t)s5*4 + q];
    uint2 v6 = ub[(size_t)s6*4 + q];
    uint2 v7 = ub[(size_t)s7*4 + q];
    a0 += dec8(v0); a1 += dec8(v1); a2 += dec8(v2); a3 += dec8(v3);
    a0 += dec8(v4); a1 += dec8(v5); a2 += dec8(v6); a3 += dec8(v7);
  }
  for (; k<e0; k++) a0 += dec8(ub[(size_t)csr[k]*4 + q]);
  a0 = (a0 + a1) + (a2 + a3);
  float idg = gv ? invdeg[node] : 0.0f;
  float bavg = (idg != 0.0f) ? base : 0.0f;   // ref: isolated node -> avg = 0
  a0 = a0*idg + bavg;
  h8 afrag = __builtin_convertvector(a0, h8);
  f8 od = {0,0,0,0,0,0,0,0};
  if (gv) od = dec8(ub[(size_t)node*4 + q]) + base;
  h8 ofrag = __builtin_convertvector(od, h8);

  f4 z1 = {0,0,0,0}, z2 = {0,0,0,0};
  z1 = __builtin_amdgcn_mfma_f32_16x16x32_f16(ofrag, wbLo, z1, 0, 0, 0);
  z1 = __builtin_amdgcn_mfma_f32_16x16x32_f16(afrag, waLo, z1, 0, 0, 0);
  z2 = __builtin_amdgcn_mfma_f32_16x16x32_f16(ofrag, wbHi, z2, 0, 0, 0);
  z2 = __builtin_amdgcn_mfma_f32_16x16x32_f16(afrag, waHi, z2, 0, 0, 0);
  z1 *= Rscale; z2 *= Rscale;

  // C layout: row (node-in-tile) = q*4 + r, col = c (z1) / c+16 (z2)
  f4 mx, sm;
  #pragma unroll
  for (int r=0;r<4;r++) mx[r] = fmaxf(z1[r], z2[r]);
  #pragma unroll
  for (int s=1;s<16;s<<=1){
    #pragma unroll
    for (int r=0;r<4;r++) mx[r] = fmaxf(mx[r], __shfl_xor(mx[r], s));
  }
  #pragma unroll
  for (int r=0;r<4;r++){
    z1[r] = expf(z1[r]-mx[r]);
    z2[r] = expf(z2[r]-mx[r]);
    sm[r] = z1[r] + z2[r];
  }
  #pragma unroll
  for (int s=1;s<16;s<<=1){
    #pragma unroll
    for (int r=0;r<4;r++) sm[r] += __shfl_xor(sm[r], s);
  }
  float cs1 = 0.0f, cs2 = 0.0f;
  #pragma unroll
  for (int r=0;r<4;r++){
    float rs = 1.0f/sm[r];
    float v1 = expf(z1[r]*rs) - 1.0f;   // store v = u - 1, v in [0, 1.72] (fp8-friendly)
    float v2 = expf(z2[r]*rs) - 1.0f;
    int p1 = __builtin_amdgcn_cvt_pk_fp8_f32(v1, v1, 0, false);
    int p2 = __builtin_amdgcn_cvt_pk_fp8_f32(v2, v2, 0, false);
    f2 d1 = __builtin_amdgcn_cvt_pk_f32_fp8(p1, false);
    f2 d2 = __builtin_amdgcn_cvt_pk_f32_fp8(p2, false);
    int lrow = wv*16 + q*4 + r;
    sU[lrow][c]      = (unsigned char)(p1 & 0xff);
    sU[lrow][c + 16] = (unsigned char)(p2 & 0xff);
    if (tile + q*4 + r < n){
      cs1 += d1[0];                 // colsum consistent with stored (rounded) v
      cs2 += d2[0];
    }
  }
  cs1 += __shfl_xor(cs1, 16); cs1 += __shfl_xor(cs1, 32);
  cs2 += __shfl_xor(cs2, 16); cs2 += __shfl_xor(cs2, 32);
  if (lane < 16){
    atomicAdd(&sCol[c],      cs1);
    atomicAdd(&sCol[c + 16], cs2);
  }
  __syncthreads();
  if (tid < 32) atomicAdd(&cs_next[tid*CSTR], sCol[tid]);
  // coalesced writeout: 8B/lane, tile staged in sU
  int row = tid >> 2;
  int jj  = tid & 3;
  int gnode = blockIdx.x*64 + row;
  if (gnode < n){
    uint2 val = *(const uint2*)&sU[row][jj*8];
    *(uint2*)(uout + (size_t)gnode*32 + jj*8) = val;
  }
}

// ---------------- output layer: z = (1+v)@ (W/colsum) + b = b + sum(ws) + v@ws ----------------

__global__ __launch_bounds__(256) void k_out1(const unsigned char* __restrict__ u, const float* __restrict__ W,
    const float* __restrict__ bptr, const float* __restrict__ cs_last,
    float* __restrict__ z, unsigned* __restrict__ zmaxkey, int n){
  __shared__ float ws[32];
  __shared__ float red[256];
  int tid = threadIdx.x;
  if (tid < 32) ws[tid] = W[tid] * (1.0f / ((float)n + cs_last[tid*CSTR]));
  __syncthreads();
  float sws = 0.0f;
  #pragma unroll
  for (int j=0;j<32;j++) sws += ws[j];
  int node = blockIdx.x*256 + tid;
  float zz = -3.0e38f;
  if (node < n){
    float acc = bptr[0] + sws;
    const uint4* ur = (const uint4*)(u + (size_t)node*32);
    uint4 w0 = ur[0], w1 = ur[1];
    unsigned wd[8] = {w0.x,w0.y,w0.z,w0.w,w1.x,w1.y,w1.z,w1.w};
    #pragma unroll
    for (int q=0;q<8;q++){
      f4 a = dec4(wd[q]);
      f4 w = ((const f4*)ws)[q];
      acc += a[0]*w[0] + a[1]*w[1] + a[2]*w[2] + a[3]*w[3];
    }
    z[node]=acc; zz=acc;
  }
  red[tid]=zz; __syncthreads();
  for (int s=128;s>0;s>>=1){
    if (tid<s) red[tid]=fmaxf(red[tid],red[tid+s]);
    __syncthreads();
  }
  if (tid==0) atomicMax(zmaxkey, f2key(red[0]));
}

__global__ __launch_bounds__(256) void k_out2(const float* __restrict__ z, const unsigned* __restrict__ zmaxkey,
                                              float* __restrict__ zsum, int n){
  __shared__ float red[256];
  int tid = threadIdx.x;
  int node = blockIdx.x*256 + tid;
  float zmax = key2f(*zmaxkey);
  float v = (node<n) ? expf(z[node]-zmax) : 0.0f;
  red[tid]=v; __syncthreads();
  for (int s=128;s>0;s>>=1){
    if (tid<s) red[tid]+=red[tid+s];
    __syncthreads();
  }
  if (tid==0) atomicAdd(zsum, red[0]);
}

__global__ __launch_bounds__(256) void k_out3(const float* __restrict__ z, const unsigned* __restrict__ zmaxkey,
                                              const float* __restrict__ zsum, float* __restrict__ out, int n){
  int node = blockIdx.x*256 + threadIdx.x;
  if (node < n){
    float zmax = key2f(*zmaxkey);
    out[node] = expf(z[node]-zmax) / (*zsum);
  }
}

// ---------------- host launcher ----------------

extern "C" void kernel_launch(void* const* d_in, const int* in_sizes, int n_in,
                              void* d_out, int out_size, void* d_ws, size_t ws_size,
                              hipStream_t stream) {
  const float* x      = (const float*)d_in[0];
  const int*   ei     = (const int*)d_in[1];   // int64 in reference -> int32 on device per harness
  const float* A_in   = (const float*)d_in[2];
  const float* B_in   = (const float*)d_in[3];
  const float* A_conv = (const float*)d_in[4];
  const float* B_conv = (const float*)d_in[5];
  const float* W_out  = (const float*)d_in[6];
  const float* b_out  = (const float*)d_in[7];
  const int N = in_sizes[0] / 4;
  const int E = in_sizes[1] / 2;
  const int NROUNDS = 16;

  char* w = (char*)d_ws;
  size_t o = 0;
  auto alloc = [&](size_t bytes)->char* {
    char* p = w + o;
    o = (o + bytes + 15) & ~(size_t)15;
    return p;
  };
  // ---- zero-init control region (one memset) ----
  int*      deg8    = (int*)     alloc((size_t)NSEG*N*4);
  float*    colsum  = (float*)   alloc((size_t)NROUNDS*32*CSTR*4);
  unsigned* zmaxkey = (unsigned*)alloc(4);
  float*    zsum    = (float*)   alloc(4);
  int*      bcur    = (int*)     alloc((size_t)NGRP*4);
  size_t ctrl_bytes = o;
  // ---- rest ----
  int*   offs    = (int*)  alloc((size_t)(N+1)*4);
  int*   cursor  = (int*)  alloc((size_t)N*4);
  float* invdeg  = (float*)alloc((size_t)N*4);
  int    nb      = (N + 1023) / 1024;
  int*   bsum    = (int*)  alloc((size_t)nb*4);
  int*   bpre    = (int*)  alloc((size_t)nb*4);
  int*   csr     = (int*)  alloc((size_t)E*4);
  int    span    = (N + NGRP - 1) / NGRP;
  int    cap     = E/NGRP + 131072;
  int*   bucket  = (int*)  alloc((size_t)NGRP*cap*4);
  unsigned char* uA = (unsigned char*)alloc((size_t)N*32);
  unsigned char* uB = (unsigned char*)alloc((size_t)N*32);
  float* zbuf    = (float*)alloc((size_t)N*4);
  (void)ws_size; (void)n_in; (void)out_size;

  hipMemsetAsync(d_ws, 0, ctrl_bytes, stream);

  int gridN = (N + 255) / 256;
  int gridC = (N + 63) / 64;
  int gridB = (E + 256*VPT - 1) / (256*VPT);
  const int B2 = 128;

  // CSR build (deg atomics folded into the bucketing pass)
  k_bucket<<<gridB, 256, 0, stream>>>(ei, deg8, bcur, bucket, E, N, span, cap);
  k_scan1<<<nb, 1024, 0, stream>>>(deg8, offs, bsum, N);
  k_scan2<<<1, 64, 0, stream>>>(bsum, bpre, nb);
  k_scan3<<<gridN, 256, 0, stream>>>(offs, bpre, deg8, cursor, invdeg, N, E);
  k_fill2<<<NGRP*B2, 256, 0, stream>>>(bucket, bcur, cursor, csr, E, N, span, cap, B2*256);

  // proj_in -> p stored fp8 (base 0)
  k_in<<<gridN, 256, 0, stream>>>(x, uA, offs, csr, invdeg, A_in, B_in, N);

  // 16 conv rounds
  const float R17 = 1.0f/131072.0f;
  for (int r = 0; r < NROUNDS; r++){
    const float* Wa = A_conv + (size_t)r*32*32;
    const float* Wb = B_conv + (size_t)r*32*32;
    const float* cs_prev = (r == 0) ? nullptr : (colsum + (size_t)(r-1)*32*CSTR);
    float*       cs_next = colsum + (size_t)r*32*CSTR;
    float        Rs      = (r == 0) ? 1.0f : R17;
    float        base    = (r == 0) ? 0.0f : 1.0f;
    const unsigned char* ui = (r & 1) ? uB : uA;
    unsigned char*       uo = (r & 1) ? uA : uB;
    k_conv<<<gridC, 256, 0, stream>>>(ui, uo, offs, csr, invdeg, Wa, Wb, cs_prev, Rs, base, cs_next, N);
  }

  // output layer (colsum_16 = n + sum(v); folded into W_out)
  k_out1<<<gridN, 256, 0, stream>>>(uA, W_out, b_out, colsum + (size_t)(NROUNDS-1)*32*CSTR, zbuf, zmaxkey, N);
  k_out2<<<gridN, 256, 0, stream>>>(zbuf, zmaxkey, zsum, N);
  k_out3<<<gridN, 256, 0, stream>>>(zbuf, zmaxkey, zsum, (float*)d_out, N);
}

// Round 2
// 1006.160 us; speedup vs baseline: 1.1547x; 1.1545x over previous
//
#include <hip/hip_runtime.h>

#define NGF 256   // fine dst-regions for atomic-free counting sort (span = ceil(N/256) <= 512)
#define NBMAX 2048 // max bucket blocks (E <= 4.19M)
#define CSTR 64   // colsum element stride (256B) -> spread across L2 slices

typedef float    f2 __attribute__((ext_vector_type(2)));
typedef float    f4 __attribute__((ext_vector_type(4)));
typedef float    f8 __attribute__((ext_vector_type(8)));
typedef _Float16 h8 __attribute__((ext_vector_type(8)));

__device__ __forceinline__ unsigned f2key(float x){
  unsigned b = __float_as_uint(x);
  return (b & 0x80000000u) ? ~b : (b | 0x80000000u);
}
__device__ __forceinline__ float key2f(unsigned k){
  return (k & 0x80000000u) ? __uint_as_float(k ^ 0x80000000u) : __uint_as_float(~k);
}

// fp8 e4m3 HW decode: 4 bytes -> 4 floats
__device__ __forceinline__ f4 dec4(unsigned w){
  f2 a = __builtin_amdgcn_cvt_pk_f32_fp8((int)w, false);
  f2 b = __builtin_amdgcn_cvt_pk_f32_fp8((int)w, true);
  f4 r; r[0]=a[0]; r[1]=a[1]; r[2]=b[0]; r[3]=b[1];
  return r;
}
__device__ __forceinline__ f8 dec8(uint2 w){
  f4 lo = dec4(w.x), hi = dec4(w.y);
  f8 r;
  r[0]=lo[0]; r[1]=lo[1]; r[2]=lo[2]; r[3]=lo[3];
  r[4]=hi[0]; r[5]=hi[1]; r[6]=hi[2]; r[7]=hi[3];
  return r;
}

// ---------------- CSR build, R14: zero per-edge global atomics (they were the 2x135us floor).
//  Counting sort by fine dst-region: block-local LDS ranks -> coalesced bucket slots +
//  per-block prefix rows; per-region block builds LDS histogram -> offs/invdeg/csr. ----------------

// pack: val = (dl<<17)|src  (dl < 512, src < 131072); meta = (gf<<11)|rank (rank < 2048)

__global__ __launch_bounds__(256) void k_bucketA(const int* __restrict__ ei,
    int* __restrict__ bucket, int* __restrict__ lbasemat,
    int E, int n, int span, unsigned magic){
  __shared__ int lcnt[NGF];
  __shared__ int lbase[NGF+1];
  __shared__ int sStage[2048];
  __shared__ int sScan[256];
  int tid = threadIdx.x;
  lcnt[tid] = 0;
  __syncthreads();
  int base = blockIdx.x*2048;
  int val[8], meta[8];
  #pragma unroll
  for (int i=0;i<8;i++){
    int e = base + i*256 + tid;
    meta[i] = -1;
    val[i] = 0;
    if (e < E){
      int d = ei[E + e];
      int s = ei[e];
      if ((unsigned)d < (unsigned)n && (unsigned)s < (unsigned)n){
        int gf = (int)__umulhi((unsigned)d, magic);   // d/span exact for d < 2^17
        int dl = d - gf*span;
        val[i] = (dl << 17) | s;
        int rank = atomicAdd(&lcnt[gf], 1);           // LDS atomic only
        meta[i] = (gf << 11) | rank;
      }
    }
  }
  __syncthreads();
  // exclusive scan of lcnt -> lbase
  int v = lcnt[tid];
  sScan[tid] = v;
  __syncthreads();
  for (int o=1;o<256;o<<=1){
    int t = (tid>=o) ? sScan[tid-o] : 0;
    __syncthreads();
    if (tid>=o) sScan[tid] += t;
    __syncthreads();
  }
  lbase[tid] = sScan[tid] - v;
  if (tid == 255) lbase[NGF] = sScan[255];
  __syncthreads();
  // stage gf-sorted
  #pragma unroll
  for (int i=0;i<8;i++){
    if (meta[i] >= 0){
      int gf   = meta[i] >> 11;
      int rank = meta[i] & 0x7FF;
      sStage[lbase[gf] + rank] = val[i];
    }
  }
  // prefix row (coalesced)
  int* row = lbasemat + (size_t)blockIdx.x*(NGF+1);
  row[tid] = lbase[tid];
  if (tid == 0) row[NGF] = lbase[NGF];
  __syncthreads();
  // coalesced slot writeout (slots beyond count hold garbage; never read)
  int* bp = bucket + (size_t)blockIdx.x*2048;
  #pragma unroll
  for (int i=0;i<2;i++){
    int idx = i*256 + tid;
    ((int4*)bp)[idx] = ((const int4*)sStage)[idx];
  }
}

__global__ __launch_bounds__(256) void k_rtot(const int* __restrict__ lbasemat,
                                              int* __restrict__ rt, int nb){
  __shared__ int red[256];
  int gf = blockIdx.x, tid = threadIdx.x;
  int s = 0;
  for (int b=tid; b<nb; b+=256){
    const int* row = lbasemat + (size_t)b*(NGF+1) + gf;
    s += row[1] - row[0];
  }
  red[tid] = s;
  __syncthreads();
  for (int o=128;o>0;o>>=1){
    if (tid < o) red[tid] += red[tid+o];
    __syncthreads();
  }
  if (tid == 0) rt[gf] = red[0];
}

__global__ void k_rscan(const int* __restrict__ rt, int* __restrict__ rbase,
                        int* __restrict__ offsN){
  __shared__ int sc[256];
  int tid = threadIdx.x;
  int v = rt[tid];
  sc[tid] = v;
  __syncthreads();
  for (int o=1;o<256;o<<=1){
    int t = (tid>=o) ? sc[tid-o] : 0;
    __syncthreads();
    if (tid>=o) sc[tid] += t;
    __syncthreads();
  }
  rbase[tid] = sc[tid] - v;
  if (tid == 255){ rbase[NGF] = sc[255]; offsN[0] = sc[255]; }
}

__global__ __launch_bounds__(256) void k_fill3(const int* __restrict__ bucket,
    const int* __restrict__ lbasemat, const int* __restrict__ rbase,
    int* __restrict__ csr, int* __restrict__ offs, float* __restrict__ invdeg,
    int n, int span, int nb){
  __shared__ int sLo[NBMAX];     // absolute bucket index of run start per source block
  __shared__ int sPre[NBMAX+1];  // counts -> exclusive prefix of run lengths
  __shared__ int sScan[256];
  __shared__ int sHist[512];     // per-node counts
  __shared__ int sCur[512];      // per-node exclusive prefix -> cursors
  int gf = blockIdx.x, tid = threadIdx.x;
  // load this region's runs
  for (int b=tid; b<nb; b+=256){
    const int* row = lbasemat + (size_t)b*(NGF+1) + gf;
    int lo = row[0], hi = row[1];
    sLo[b]  = b*2048 + lo;
    sPre[b] = hi - lo;
  }
  for (int t=tid; t<512; t+=256){ sHist[t] = 0; }
  __syncthreads();
  // chunked exclusive scan over nb run lengths
  int C = (nb + 255) >> 8;
  int st = tid*C, en = st + C; if (en > nb) en = nb; if (st > nb) st = nb;
  int a0 = 0;
  for (int i=st;i<en;i++) a0 += sPre[i];
  sScan[tid] = a0;
  __syncthreads();
  for (int o=1;o<256;o<<=1){
    int t = (tid>=o) ? sScan[tid-o] : 0;
    __syncthreads();
    if (tid>=o) sScan[tid] += t;
    __syncthreads();
  }
  int ex = sScan[tid] - a0;
  int run = ex;
  for (int i=st;i<en;i++){ int t = sPre[i]; sPre[i] = run; run += t; }
  if (tid == 255) sPre[nb] = sScan[255];
  __syncthreads();
  int total = sPre[nb];
  int rb = rbase[gf];
  // pass 1: histogram
  for (int i=tid; i<total; i+=256){
    int lo = 0, hi = nb;
    while (hi - lo > 1){ int mid = (lo+hi) >> 1; if (sPre[mid] <= i) lo = mid; else hi = mid; }
    int v = bucket[sLo[lo] + (i - sPre[lo])];
    atomicAdd(&sHist[v >> 17], 1);
  }
  __syncthreads();
  // node-prefix scan (span <= 512): sCur = exclusive prefix of sHist
  int C2 = (span + 255) >> 8;
  int st2 = tid*C2, en2 = st2 + C2; if (en2 > span) en2 = span; if (st2 > span) st2 = span;
  int a2 = 0;
  for (int i=st2;i<en2;i++) a2 += sHist[i];
  sScan[tid] = a2;
  __syncthreads();
  for (int o=1;o<256;o<<=1){
    int t = (tid>=o) ? sScan[tid-o] : 0;
    __syncthreads();
    if (tid>=o) sScan[tid] += t;
    __syncthreads();
  }
  int ex2 = sScan[tid] - a2;
  int run2 = ex2;
  for (int i=st2;i<en2;i++){ sCur[i] = run2; run2 += sHist[i]; }
  __syncthreads();
  // offs + invdeg (replaces old deg8/scan pipeline)
  for (int t=tid; t<span; t+=256){
    int node = gf*span + t;
    if (node < n){
      int deg = sHist[t];
      offs[node]   = rb + sCur[t];
      invdeg[node] = (deg > 0) ? 1.0f/(float)deg : 0.0f;  // 0 marks isolated node
    }
  }
  __syncthreads();
  // pass 2: place (LDS cursors; csr writes land in ~50KB L2-resident window)
  for (int i=tid; i<total; i+=256){
    int lo = 0, hi = nb;
    while (hi - lo > 1){ int mid = (lo+hi) >> 1; if (sPre[mid] <= i) lo = mid; else hi = mid; }
    int v  = bucket[sLo[lo] + (i - sPre[lo])];
    int dl = v >> 17;
    int sc = v & 0x1FFFF;
    int pos = atomicAdd(&sCur[dl], 1);
    csr[rb + pos] = sc;
  }
}

// ---------------- proj_in: gather x[4] + (avg@A + x@B) + row softmax -> store p as fp8 (base 0) ----------------

__global__ __launch_bounds__(256) void k_in(const float* __restrict__ x, unsigned char* __restrict__ uout,
    const int* __restrict__ offs, const int* __restrict__ csr, const float* __restrict__ invdeg,
    const float* __restrict__ A, const float* __restrict__ B, int n){
  __shared__ float sA[128], sB[128];
  int tid = threadIdx.x;
  if (tid < 128){ sA[tid]=A[tid]; sB[tid]=B[tid]; }
  __syncthreads();
  int node = blockIdx.x*256 + tid;
  if (node >= n) return;
  float4 s = {0,0,0,0};
  int b0=offs[node], e0=offs[node+1];
  for (int k=b0;k<e0;k++){
    int sid = csr[k];
    float4 v = ((const float4*)x)[sid];
    s.x+=v.x; s.y+=v.y; s.z+=v.z; s.w+=v.w;
  }
  float idg = invdeg[node];
  s.x*=idg; s.y*=idg; s.z*=idg; s.w*=idg;
  float4 xr = ((const float4*)x)[node];
  float z[32];
  #pragma unroll
  for (int j=0;j<32;j++){
    z[j] = s.x*sA[j] + s.y*sA[32+j] + s.z*sA[64+j] + s.w*sA[96+j]
         + xr.x*sB[j] + xr.y*sB[32+j] + xr.z*sB[64+j] + xr.w*sB[96+j];
  }
  float m = z[0];
  #pragma unroll
  for (int j=1;j<32;j++) m = fmaxf(m,z[j]);
  float sum=0.0f;
  #pragma unroll
  for (int j=0;j<32;j++){ z[j]=expf(z[j]-m); sum+=z[j]; }
  float r = 1.0f/sum;
  unsigned pk[8];
  #pragma unroll
  for (int q=0;q<8;q++){
    int w0 = __builtin_amdgcn_cvt_pk_fp8_f32(z[4*q]*r,   z[4*q+1]*r, 0,  false);
    w0     = __builtin_amdgcn_cvt_pk_fp8_f32(z[4*q+2]*r, z[4*q+3]*r, w0, true);
    pk[q] = (unsigned)w0;
  }
  uint4* op = (uint4*)(uout + (size_t)node*32);
  op[0] = make_uint4(pk[0],pk[1],pk[2],pk[3]);
  op[1] = make_uint4(pk[4],pk[5],pk[6],pk[7]);
}

// ---------------- conv round (MFMA, fp8 state): wave = 16 nodes. Plain loads. Output tile
//  staged in LDS -> coalesced 8B/lane stores. Structural floor: one random 32B row-request
//  per edge, throughput = E x L2-latency / (CUs x MSHRs) ~ 50us/round; invariant to payload
//  size (R6), cache placement (R9), and lane utilization (R12). ----------------

__global__ __launch_bounds__(256) void k_conv(
    const unsigned char* __restrict__ uin, unsigned char* __restrict__ uout,
    const int* __restrict__ offs, const int* __restrict__ csr,
    const float* __restrict__ invdeg,
    const float* __restrict__ Wa, const float* __restrict__ Wb,
    const float* __restrict__ cs_prev, float Rscale, float base,
    float* __restrict__ cs_next, int n){
  __shared__ float sWa[1024], sWb[1024];
  __shared__ float sCol[32];
  __shared__ unsigned char sU[64][32];
  int tid = threadIdx.x;
  float rcf = 1.0f;
  if (cs_prev) rcf = 131072.0f / ((float)n + cs_prev[(tid>>3)*CSTR]);  // rho = 2^17/colsum
  ((f4*)sWa)[tid] = ((const f4*)Wa)[tid] * rcf;
  ((f4*)sWb)[tid] = ((const f4*)Wb)[tid] * rcf;
  if (tid < 32) sCol[tid] = 0.0f;
  __syncthreads();

  int lane = tid & 63;
  int wv   = tid >> 6;
  int q    = lane >> 4;         // k-chunk (A) / row-quad (C)
  int c    = lane & 15;         // gather node (A's m) / output column (B's n, C's col)
  int tile = blockIdx.x*64 + wv*16;
  int node = tile + c;
  bool gv = node < n;

  // B-fragments in registers: B[k][n], k = q*8+j, n = c (lo) / c+16 (hi)
  h8 waLo, waHi, wbLo, wbHi;
  #pragma unroll
  for (int j=0;j<8;j++){
    int k = q*8 + j;
    waLo[j] = (_Float16)sWa[k*32 + c];
    waHi[j] = (_Float16)sWa[k*32 + c + 16];
    wbLo[j] = (_Float16)sWb[k*32 + c];
    wbHi[j] = (_Float16)sWb[k*32 + c + 16];
  }

  // gather: mean of neighbor v rows (fp8 decode), 8 plain loads in flight per lane
  f8 a0 = {0,0,0,0,0,0,0,0}, a1 = {0,0,0,0,0,0,0,0};
  f8 a2 = {0,0,0,0,0,0,0,0}, a3 = {0,0,0,0,0,0,0,0};
  int b0 = gv ? offs[node]   : 0;
  int e0 = gv ? offs[node+1] : 0;
  const uint2* ub = (const uint2*)uin;
  int k = b0;
  for (; k+8<=e0; k+=8){
    int s0=csr[k],   s1=csr[k+1], s2=csr[k+2], s3=csr[k+3];
    int s4=csr[k+4], s5=csr[k+5], s6=csr[k+6], s7=csr[k+7];
    uint2 v0 = ub[(size_t)s0*4 + q];
    uint2 v1 = ub[(size_t)s1*4 + q];
    uint2 v2 = ub[(size_t)s2*4 + q];
    uint2 v3 = ub[(size_t)s3*4 + q];
    uint2 v4 = ub[(size_t)s4*4 + q];
    uint2 v5 = ub[(size_t)s5*4 + q];
    uint2 v6 = ub[(size_t)s6*4 + q];
    uint2 v7 = ub[(size_t)s7*4 + q];
    a0 += dec8(v0); a1 += dec8(v1); a2 += dec8(v2); a3 += dec8(v3);
    a0 += dec8(v4); a1 += dec8(v5); a2 += dec8(v6); a3 += dec8(v7);
  }
  for (; k<e0; k++) a0 += dec8(ub[(size_t)csr[k]*4 + q]);
  a0 = (a0 + a1) + (a2 + a3);
  float idg = gv ? invdeg[node] : 0.0f;
  float bavg = (idg != 0.0f) ? base : 0.0f;   // ref: isolated node -> avg = 0
  a0 = a0*idg + bavg;
  h8 afrag = __builtin_convertvector(a0, h8);
  f8 od = {0,0,0,0,0,0,0,0};
  if (gv) od = dec8(ub[(size_t)node*4 + q]) + base;
  h8 ofrag = __builtin_convertvector(od, h8);

  f4 z1 = {0,0,0,0}, z2 = {0,0,0,0};
  z1 = __builtin_amdgcn_mfma_f32_16x16x32_f16(ofrag, wbLo, z1, 0, 0, 0);
  z1 = __builtin_amdgcn_mfma_f32_16x16x32_f16(afrag, waLo, z1, 0, 0, 0);
  z2 = __builtin_amdgcn_mfma_f32_16x16x32_f16(ofrag, wbHi, z2, 0, 0, 0);
  z2 = __builtin_amdgcn_mfma_f32_16x16x32_f16(afrag, waHi, z2, 0, 0, 0);
  z1 *= Rscale; z2 *= Rscale;

  // C layout: row (node-in-tile) = q*4 + r, col = c (z1) / c+16 (z2)
  f4 mx, sm;
  #pragma unroll
  for (int r=0;r<4;r++) mx[r] = fmaxf(z1[r], z2[r]);
  #pragma unroll
  for (int s=1;s<16;s<<=1){
    #pragma unroll
    for (int r=0;r<4;r++) mx[r] = fmaxf(mx[r], __shfl_xor(mx[r], s));
  }
  #pragma unroll
  for (int r=0;r<4;r++){
    z1[r] = expf(z1[r]-mx[r]);
    z2[r] = expf(z2[r]-mx[r]);
    sm[r] = z1[r] + z2[r];
  }
  #pragma unroll
  for (int s=1;s<16;s<<=1){
    #pragma unroll
    for (int r=0;r<4;r++) sm[r] += __shfl_xor(sm[r], s);
  }
  float cs1 = 0.0f, cs2 = 0.0f;
  #pragma unroll
  for (int r=0;r<4;r++){
    float rs = 1.0f/sm[r];
    float v1 = expf(z1[r]*rs) - 1.0f;   // store v = u - 1, v in [0, 1.72] (fp8-friendly)
    float v2 = expf(z2[r]*rs) - 1.0f;
    int p1 = __builtin_amdgcn_cvt_pk_fp8_f32(v1, v1, 0, false);
    int p2 = __builtin_amdgcn_cvt_pk_fp8_f32(v2, v2, 0, false);
    f2 d1 = __builtin_amdgcn_cvt_pk_f32_fp8(p1, false);
    f2 d2 = __builtin_amdgcn_cvt_pk_f32_fp8(p2, false);
    int lrow = wv*16 + q*4 + r;
    sU[lrow][c]      = (unsigned char)(p1 & 0xff);
    sU[lrow][c + 16] = (unsigned char)(p2 & 0xff);
    if (tile + q*4 + r < n){
      cs1 += d1[0];                 // colsum consistent with stored (rounded) v
      cs2 += d2[0];
    }
  }
  cs1 += __shfl_xor(cs1, 16); cs1 += __shfl_xor(cs1, 32);
  cs2 += __shfl_xor(cs2, 16); cs2 += __shfl_xor(cs2, 32);
  if (lane < 16){
    atomicAdd(&sCol[c],      cs1);
    atomicAdd(&sCol[c + 16], cs2);
  }
  __syncthreads();
  if (tid < 32) atomicAdd(&cs_next[tid*CSTR], sCol[tid]);
  // coalesced writeout: 8B/lane, tile staged in sU
  int row = tid >> 2;
  int jj  = tid & 3;
  int gnode = blockIdx.x*64 + row;
  if (gnode < n){
    uint2 val = *(const uint2*)&sU[row][jj*8];
    *(uint2*)(uout + (size_t)gnode*32 + jj*8) = val;
  }
}

// ---------------- output layer: z = (1+v)@ (W/colsum) + b = b + sum(ws) + v@ws ----------------

__global__ __launch_bounds__(256) void k_out1(const unsigned char* __restrict__ u, const float* __restrict__ W,
    const float* __restrict__ bptr, const float* __restrict__ cs_last,
    float* __restrict__ z, unsigned* __restrict__ zmaxkey, int n){
  __shared__ float ws[32];
  __shared__ float red[256];
  int tid = threadIdx.x;
  if (tid < 32) ws[tid] = W[tid] * (1.0f / ((float)n + cs_last[tid*CSTR]));
  __syncthreads();
  float sws = 0.0f;
  #pragma unroll
  for (int j=0;j<32;j++) sws += ws[j];
  int node = blockIdx.x*256 + tid;
  float zz = -3.0e38f;
  if (node < n){
    float acc = bptr[0] + sws;
    const uint4* ur = (const uint4*)(u + (size_t)node*32);
    uint4 w0 = ur[0], w1 = ur[1];
    unsigned wd[8] = {w0.x,w0.y,w0.z,w0.w,w1.x,w1.y,w1.z,w1.w};
    #pragma unroll
    for (int q=0;q<8;q++){
      f4 a = dec4(wd[q]);
      f4 w = ((const f4*)ws)[q];
      acc += a[0]*w[0] + a[1]*w[1] + a[2]*w[2] + a[3]*w[3];
    }
    z[node]=acc; zz=acc;
  }
  red[tid]=zz; __syncthreads();
  for (int s=128;s>0;s>>=1){
    if (tid<s) red[tid]=fmaxf(red[tid],red[tid+s]);
    __syncthreads();
  }
  if (tid==0) atomicMax(zmaxkey, f2key(red[0]));
}

__global__ __launch_bounds__(256) void k_out2(const float* __restrict__ z, const unsigned* __restrict__ zmaxkey,
                                              float* __restrict__ zsum, int n){
  __shared__ float red[256];
  int tid = threadIdx.x;
  int node = blockIdx.x*256 + tid;
  float zmax = key2f(*zmaxkey);
  float v = (node<n) ? expf(z[node]-zmax) : 0.0f;
  red[tid]=v; __syncthreads();
  for (int s=128;s>0;s>>=1){
    if (tid<s) red[tid]+=red[tid+s];
    __syncthreads();
  }
  if (tid==0) atomicAdd(zsum, red[0]);
}

__global__ __launch_bounds__(256) void k_out3(const float* __restrict__ z, const unsigned* __restrict__ zmaxkey,
                                              const float* __restrict__ zsum, float* __restrict__ out, int n){
  int node = blockIdx.x*256 + threadIdx.x;
  if (node < n){
    float zmax = key2f(*zmaxkey);
    out[node] = expf(z[node]-zmax) / (*zsum);
  }
}

// ---------------- host launcher ----------------

extern "C" void kernel_launch(void* const* d_in, const int* in_sizes, int n_in,
                              void* d_out, int out_size, void* d_ws, size_t ws_size,
                              hipStream_t stream) {
  const float* x      = (const float*)d_in[0];
  const int*   ei     = (const int*)d_in[1];   // int64 in reference -> int32 on device per harness
  const float* A_in   = (const float*)d_in[2];
  const float* B_in   = (const float*)d_in[3];
  const float* A_conv = (const float*)d_in[4];
  const float* B_conv = (const float*)d_in[5];
  const float* W_out  = (const float*)d_in[6];
  const float* b_out  = (const float*)d_in[7];
  const int N = in_sizes[0] / 4;
  const int E = in_sizes[1] / 2;
  const int NROUNDS = 16;

  char* w = (char*)d_ws;
  size_t o = 0;
  auto alloc = [&](size_t bytes)->char* {
    char* p = w + o;
    o = (o + bytes + 15) & ~(size_t)15;
    return p;
  };
  // ---- zero-init control region (one memset) ----
  float*    colsum  = (float*)   alloc((size_t)NROUNDS*32*CSTR*4);
  unsigned* zmaxkey = (unsigned*)alloc(4);
  float*    zsum    = (float*)   alloc(4);
  size_t ctrl_bytes = o;
  // ---- rest (all fully written before read; no zeroing needed) ----
  int    nb      = (E + 2047) / 2048;          // <= NBMAX
  int    span    = (N + NGF - 1) / NGF;        // <= 512 for N <= 131072
  int*   offs    = (int*)  alloc((size_t)(N+1)*4);
  float* invdeg  = (float*)alloc((size_t)N*4);
  int*   csr     = (int*)  alloc((size_t)E*4);
  int*   bucket  = (int*)  alloc((size_t)nb*2048*4);
  int*   lbasemat= (int*)  alloc((size_t)nb*(NGF+1)*4);
  int*   rt      = (int*)  alloc((size_t)NGF*4);
  int*   rbase   = (int*)  alloc((size_t)(NGF+1)*4);
  unsigned char* uA = (unsigned char*)alloc((size_t)N*32);
  unsigned char* uB = (unsigned char*)alloc((size_t)N*32);
  float* zbuf    = (float*)alloc((size_t)N*4);
  (void)ws_size; (void)n_in; (void)out_size;

  hipMemsetAsync(d_ws, 0, ctrl_bytes, stream);

  unsigned magic = (unsigned)((((unsigned long long)1 << 32) + (unsigned long long)span - 1)
                              / (unsigned long long)span);
  int gridN = (N + 255) / 256;
  int gridC = (N + 63) / 64;

  // CSR build: no per-edge global atomics anywhere
  k_bucketA<<<nb, 256, 0, stream>>>(ei, bucket, lbasemat, E, N, span, magic);
  k_rtot   <<<NGF, 256, 0, stream>>>(lbasemat, rt, nb);
  k_rscan  <<<1, 256, 0, stream>>>(rt, rbase, offs + N);
  k_fill3  <<<NGF, 256, 0, stream>>>(bucket, lbasemat, rbase, csr, offs, invdeg, N, span, nb);

  // proj_in -> p stored fp8 (base 0)
  k_in<<<gridN, 256, 0, stream>>>(x, uA, offs, csr, invdeg, A_in, B_in, N);

  // 16 conv rounds
  const float R17 = 1.0f/131072.0f;
  for (int r = 0; r < NROUNDS; r++){
    const float* Wa = A_conv + (size_t)r*32*32;
    const float* Wb = B_conv + (size_t)r*32*32;
    const float* cs_prev = (r == 0) ? nullptr : (colsum + (size_t)(r-1)*32*CSTR);
    float*       cs_next = colsum + (size_t)r*32*CSTR;
    float        Rs      = (r == 0) ? 1.0f : R17;
    float        base    = (r == 0) ? 0.0f : 1.0f;
    const unsigned char* ui = (r & 1) ? uB : uA;
    unsigned char*       uo = (r & 1) ? uA : uB;
    k_conv<<<gridC, 256, 0, stream>>>(ui, uo, offs, csr, invdeg, Wa, Wb, cs_prev, Rs, base, cs_next, N);
  }

  // output layer (colsum_16 = n + sum(v); folded into W_out)
  k_out1<<<gridN, 256, 0, stream>>>(uA, W_out, b_out, colsum + (size_t)(NROUNDS-1)*32*CSTR, zbuf, zmaxkey, N);
  k_out2<<<gridN, 256, 0, stream>>>(zbuf, zmaxkey, zsum, N);
  k_out3<<<gridN, 256, 0, stream>>>(zbuf, zmaxkey, zsum, (float*)d_out, N);
}